// Round 1
// baseline (1204.257 us; speedup 1.0000x reference)
//
#include <hip/hip_runtime.h>
#include <math.h>

// Problem constants (fixed-shape problem)
#define DD 256
#define HH 4
#define CC 64
#define LL 5
#define NEG_SLOPE 0.2f

static __device__ __forceinline__ float lrelu(float x) {
    return x > 0.0f ? x : NEG_SLOPE * x;
}

// ---------------------------------------------------------------------------
// K0: wproj[l][k][h] = sum_c gat_ew[l][k][h*64+c] * att_edge[l][h][c]
__global__ __launch_bounds__(256) void wproj_kernel(
    const float* __restrict__ gat_ew, const float* __restrict__ att_edge,
    float* __restrict__ wproj) {
    int l = blockIdx.x;
    int k = threadIdx.x;
    const float* W = gat_ew + (size_t)l * DD * DD;
    const float* att = att_edge + l * DD;  // [H][C] flat = 256
    for (int hh = 0; hh < HH; ++hh) {
        float s = 0.f;
        #pragma unroll
        for (int c = 0; c < CC; ++c)
            s += W[k * DD + hh * CC + c] * att[hh * CC + c];
        wproj[(l * DD + k) * HH + hh] = s;
    }
}

// ---------------------------------------------------------------------------
// K1: node encoder h = relu(x @ enc_w + enc_b)
__global__ __launch_bounds__(256) void encoder_kernel(
    const float* __restrict__ x, const float* __restrict__ enc_w,
    const float* __restrict__ enc_b, float* __restrict__ h, int N) {
    int n = blockIdx.x;
    int tid = threadIdx.x;
    __shared__ float xs[42];
    if (tid < 42) xs[tid] = x[(size_t)n * 42 + tid];
    __syncthreads();
    float acc = enc_b[tid];
    #pragma unroll
    for (int f = 0; f < 42; ++f) acc += xs[f] * enc_w[f * DD + tid];
    h[(size_t)n * DD + tid] = fmaxf(acc, 0.f);
}

// ---------------------------------------------------------------------------
// K2: per-edge: e_row = relu(edge_attr@eenc_w+eenc_b); a_e[l][e][h] = e_row . wproj[l][:,h]
// also accumulate per-dst sums for self-loop mean and in-degree.
__global__ __launch_bounds__(256) void edge_pre_kernel(
    const float* __restrict__ edge_attr, const int* __restrict__ dst_arr,
    const float* __restrict__ eenc_w, const float* __restrict__ eenc_b,
    const float* __restrict__ wproj, float* __restrict__ a_e_all,
    float* __restrict__ ae_self_acc, int* __restrict__ deg,
    int E, int Etot, int N) {
    __shared__ float wp[LL * DD * HH];  // 5120 floats = 20KB
    for (int i = threadIdx.x; i < LL * DD * HH; i += 256) wp[i] = wproj[i];
    __syncthreads();
    int wave = threadIdx.x >> 6;
    int lane = threadIdx.x & 63;
    int e = blockIdx.x * 4 + wave;
    if (e >= E) return;
    int dst = dst_arr[e];
    float v0 = eenc_b[lane], v1 = eenc_b[lane + 64], v2 = eenc_b[lane + 128], v3 = eenc_b[lane + 192];
    #pragma unroll
    for (int f = 0; f < 12; ++f) {
        float a = edge_attr[(size_t)e * 12 + f];
        v0 += a * eenc_w[f * DD + lane];
        v1 += a * eenc_w[f * DD + lane + 64];
        v2 += a * eenc_w[f * DD + lane + 128];
        v3 += a * eenc_w[f * DD + lane + 192];
    }
    v0 = fmaxf(v0, 0.f); v1 = fmaxf(v1, 0.f); v2 = fmaxf(v2, 0.f); v3 = fmaxf(v3, 0.f);
    if (lane == 0) atomicAdd(&deg[dst], 1);
    for (int l = 0; l < LL; ++l) {
        for (int hh = 0; hh < HH; ++hh) {
            float p = v0 * wp[(l * DD + lane) * HH + hh]
                    + v1 * wp[(l * DD + lane + 64) * HH + hh]
                    + v2 * wp[(l * DD + lane + 128) * HH + hh]
                    + v3 * wp[(l * DD + lane + 192) * HH + hh];
            #pragma unroll
            for (int off = 32; off; off >>= 1) p += __shfl_xor(p, off, 64);
            if (lane == 0) {
                a_e_all[((size_t)l * Etot + e) * HH + hh] = p;
                atomicAdd(&ae_self_acc[((size_t)l * N + dst) * HH + hh], p);
            }
        }
    }
}

// ---------------------------------------------------------------------------
// K3: self-loop a_e = mean of incoming  (a_e_all index E+n)
__global__ void self_ae_kernel(const float* __restrict__ ae_self_acc,
                               const int* __restrict__ deg, float* __restrict__ a_e_all,
                               int N, int E, int Etot) {
    int i = blockIdx.x * 256 + threadIdx.x;
    if (i >= N * LL * HH) return;
    int n = i / (LL * HH);
    int q = i % (LL * HH);
    int l = q / HH, hh = q % HH;
    float d = (float)max(deg[n], 1);
    a_e_all[((size_t)l * Etot + E + n) * HH + hh] =
        ae_self_acc[((size_t)l * N + n) * HH + hh] / d;
}

// ---------------------------------------------------------------------------
// K4: exclusive prefix scan of deg -> row_ptr  (single block)
__global__ __launch_bounds__(1024) void scan_kernel(const int* __restrict__ deg,
                                                    int* __restrict__ row_ptr, int n) {
    __shared__ int buf[1024];
    __shared__ int carry_s;
    int tid = threadIdx.x;
    if (tid == 0) carry_s = 0;
    __syncthreads();
    for (int base = 0; base < n; base += 1024) {
        int i = base + tid;
        int v = (i < n) ? deg[i] : 0;
        buf[tid] = v;
        __syncthreads();
        for (int off = 1; off < 1024; off <<= 1) {
            int t = (tid >= off) ? buf[tid - off] : 0;
            __syncthreads();
            buf[tid] += t;
            __syncthreads();
        }
        int carry = carry_s;
        if (i < n) row_ptr[i] = carry + buf[tid] - v;
        __syncthreads();
        if (tid == 1023) carry_s = carry + buf[1023];
        __syncthreads();
    }
    if (tid == 0) row_ptr[n] = carry_s;
}

__global__ void copy_int_kernel(const int* __restrict__ a, int* __restrict__ b, int n) {
    int i = blockIdx.x * 256 + threadIdx.x;
    if (i < n) b[i] = a[i];
}

// K4c: scatter edges into CSR order by dst
__global__ void scatter_kernel(const int* __restrict__ src, const int* __restrict__ dst,
                               int* __restrict__ cursor, int* __restrict__ csr_src,
                               int* __restrict__ csr_eid, int E) {
    int e = blockIdx.x * 256 + threadIdx.x;
    if (e >= E) return;
    int d = dst[e];
    int pos = atomicAdd(&cursor[d], 1);
    csr_src[pos] = src[e];
    csr_eid[pos] = e;
}

// ---------------------------------------------------------------------------
// GEMM: C[M,256] = A[M,256] @ W[256,256] (+bias, optional relu). fp32, 64x64 tile.
__global__ __launch_bounds__(256) void gemm256_kernel(
    const float* __restrict__ A, const float* __restrict__ W,
    const float* __restrict__ bias, float* __restrict__ C, int M, int do_relu) {
    __shared__ float As[16][68];
    __shared__ float Bs[16][68];
    int tid = threadIdx.x;
    int tx = tid & 15, ty = tid >> 4;
    int m0 = blockIdx.x * 64;
    int n0 = blockIdx.y * 64;
    float acc[4][4] = {};
    int arow = tid >> 2, aseg = tid & 3;
    int brow = tid >> 4, bseg = tid & 15;
    for (int k0 = 0; k0 < 256; k0 += 16) {
        float4 av = make_float4(0.f, 0.f, 0.f, 0.f);
        int grow = m0 + arow;
        if (grow < M) av = *(const float4*)(A + (size_t)grow * DD + k0 + aseg * 4);
        As[aseg * 4 + 0][arow] = av.x;
        As[aseg * 4 + 1][arow] = av.y;
        As[aseg * 4 + 2][arow] = av.z;
        As[aseg * 4 + 3][arow] = av.w;
        float4 bv = *(const float4*)(W + (size_t)(k0 + brow) * DD + n0 + bseg * 4);
        *(float4*)&Bs[brow][bseg * 4] = bv;
        __syncthreads();
        #pragma unroll
        for (int kk = 0; kk < 16; ++kk) {
            float a0 = As[kk][ty * 4 + 0], a1 = As[kk][ty * 4 + 1];
            float a2 = As[kk][ty * 4 + 2], a3 = As[kk][ty * 4 + 3];
            float b0 = Bs[kk][tx * 4 + 0], b1 = Bs[kk][tx * 4 + 1];
            float b2 = Bs[kk][tx * 4 + 2], b3 = Bs[kk][tx * 4 + 3];
            acc[0][0] += a0 * b0; acc[0][1] += a0 * b1; acc[0][2] += a0 * b2; acc[0][3] += a0 * b3;
            acc[1][0] += a1 * b0; acc[1][1] += a1 * b1; acc[1][2] += a1 * b2; acc[1][3] += a1 * b3;
            acc[2][0] += a2 * b0; acc[2][1] += a2 * b1; acc[2][2] += a2 * b2; acc[2][3] += a2 * b3;
            acc[3][0] += a3 * b0; acc[3][1] += a3 * b1; acc[3][2] += a3 * b2; acc[3][3] += a3 * b3;
        }
        __syncthreads();
    }
    #pragma unroll
    for (int i = 0; i < 4; ++i) {
        int r = m0 + ty * 4 + i;
        if (r >= M) continue;
        #pragma unroll
        for (int j = 0; j < 4; ++j) {
            int col = n0 + tx * 4 + j;
            float v = acc[i][j];
            if (bias) v += bias[col];
            if (do_relu) v = fmaxf(v, 0.f);
            C[(size_t)r * DD + col] = v;
        }
    }
}

// ---------------------------------------------------------------------------
// K5b: a_s[n,h], a_d[n,h] from xh
__global__ __launch_bounds__(256) void asd_kernel(
    const float* __restrict__ xh, const float* __restrict__ att_src,
    const float* __restrict__ att_dst, float* __restrict__ a_s, float* __restrict__ a_d) {
    int n = blockIdx.x;
    int tid = threadIdx.x;
    int hh = tid >> 6;
    float v = xh[(size_t)n * DD + tid];
    float ps = v * att_src[tid];  // att_src[l] is [H][C] flat == tid
    float pd = v * att_dst[tid];
    #pragma unroll
    for (int off = 32; off; off >>= 1) {
        ps += __shfl_xor(ps, off, 64);
        pd += __shfl_xor(pd, off, 64);
    }
    if ((tid & 63) == 0) {
        a_s[n * HH + hh] = ps;
        a_d[n * HH + hh] = pd;
    }
}

// ---------------------------------------------------------------------------
// K6: per-node softmax attention + aggregation + bias + LN + relu + residual
__global__ __launch_bounds__(256) void gat_message_kernel(
    const float* __restrict__ xh, const float* __restrict__ a_s,
    const float* __restrict__ a_d, const float* __restrict__ a_e,  // layer base
    const int* __restrict__ row_ptr, const int* __restrict__ csr_src,
    const int* __restrict__ csr_eid, const float* __restrict__ gat_b,
    const float* __restrict__ ln_g, const float* __restrict__ ln_b,
    float* __restrict__ h, int N, int E) {
    int n = blockIdx.x;
    int tid = threadIdx.x;
    int hh = tid >> 6, c = tid & 63;
    int rs = row_ptr[n], re = row_ptr[n + 1];
    float adn = a_d[n * HH + hh];
    float al_self = lrelu(a_s[n * HH + hh] + adn + a_e[(size_t)(E + n) * HH + hh]);
    // pass 1: max
    float m = al_self;
    for (int k = rs + c; k < re; k += 64) {
        int s = csr_src[k], eid = csr_eid[k];
        m = fmaxf(m, lrelu(a_s[s * HH + hh] + adn + a_e[(size_t)eid * HH + hh]));
    }
    #pragma unroll
    for (int off = 32; off; off >>= 1) m = fmaxf(m, __shfl_xor(m, off, 64));
    // pass 2: denom
    float sden = 0.f;
    for (int k = rs + c; k < re; k += 64) {
        int s = csr_src[k], eid = csr_eid[k];
        sden += __expf(lrelu(a_s[s * HH + hh] + adn + a_e[(size_t)eid * HH + hh]) - m);
    }
    #pragma unroll
    for (int off = 32; off; off >>= 1) sden += __shfl_xor(sden, off, 64);
    sden += __expf(al_self - m);
    float inv_den = 1.0f / sden;
    // pass 3: weighted aggregation (all lanes walk all edges; xh row reads coalesced)
    float acc = __expf(al_self - m) * inv_den * xh[(size_t)n * DD + hh * CC + c];
    for (int k = rs; k < re; ++k) {
        int s = csr_src[k], eid = csr_eid[k];
        float w = __expf(lrelu(a_s[s * HH + hh] + adn + a_e[(size_t)eid * HH + hh]) - m) * inv_den;
        acc += w * xh[(size_t)s * DD + hh * CC + c];
    }
    float val = acc + gat_b[tid];
    // layernorm over 256
    __shared__ float s1[256], s2[256];
    s1[tid] = val;
    s2[tid] = val * val;
    __syncthreads();
    for (int off = 128; off; off >>= 1) {
        if (tid < off) { s1[tid] += s1[tid + off]; s2[tid] += s2[tid + off]; }
        __syncthreads();
    }
    float mu = s1[0] * (1.0f / DD);
    float var = s2[0] * (1.0f / DD) - mu * mu;
    float normed = (val - mu) * rsqrtf(var + 1e-5f) * ln_g[tid] + ln_b[tid];
    h[(size_t)n * DD + tid] += fmaxf(normed, 0.f);
}

// ---------------------------------------------------------------------------
// K7b: gate scalar per node
__global__ __launch_bounds__(256) void gate_kernel(
    const float* __restrict__ hid, const float* __restrict__ w2,
    const float* __restrict__ b2, float* __restrict__ gate, int N) {
    int n = blockIdx.x;
    int tid = threadIdx.x;
    __shared__ float red[256];
    red[tid] = hid[(size_t)n * DD + tid] * w2[tid];
    __syncthreads();
    for (int off = 128; off; off >>= 1) {
        if (tid < off) red[tid] += red[tid + off];
        __syncthreads();
    }
    if (tid == 0) gate[n] = red[0] + b2[0];
}

// K7pre: batch segment boundaries (batch is sorted)
__global__ void bstart_kernel(const int* __restrict__ batch, int* __restrict__ bstart,
                              int N, int B) {
    int b = threadIdx.x;
    if (b > B) return;
    int lo = 0, hi = N;
    while (lo < hi) {
        int mid = (lo + hi) >> 1;
        if (batch[mid] < b) lo = mid + 1; else hi = mid;
    }
    bstart[b] = lo;
}

// K7pool: per-graph softmax pooling
__global__ __launch_bounds__(256) void pool_kernel(
    const float* __restrict__ gate, const float* __restrict__ h,
    const int* __restrict__ bstart, float* __restrict__ g_embed) {
    int b = blockIdx.x;
    int tid = threadIdx.x;
    int s0 = bstart[b], s1 = bstart[b + 1];
    __shared__ float red[256];
    if (s1 == s0) { g_embed[b * DD + tid] = 0.f; return; }
    float m = -1e30f;
    for (int i = s0 + tid; i < s1; i += 256) m = fmaxf(m, gate[i]);
    red[tid] = m;
    __syncthreads();
    for (int off = 128; off; off >>= 1) {
        if (tid < off) red[tid] = fmaxf(red[tid], red[tid + off]);
        __syncthreads();
    }
    float gm = red[0];
    __syncthreads();
    float s = 0.f;
    for (int i = s0 + tid; i < s1; i += 256) s += __expf(gate[i] - gm);
    red[tid] = s;
    __syncthreads();
    for (int off = 128; off; off >>= 1) {
        if (tid < off) red[tid] += red[tid + off];
        __syncthreads();
    }
    float inv = 1.0f / red[0];
    float acc = 0.f;
    for (int i = s0; i < s1; ++i)
        acc += __expf(gate[i] - gm) * h[(size_t)i * DD + tid];
    g_embed[b * DD + tid] = acc * inv;
}

// K8: readout MLP [B,256] -> [B,256]
__global__ __launch_bounds__(256) void readout_kernel(
    const float* __restrict__ g_embed, const float* __restrict__ w1,
    const float* __restrict__ b1, const float* __restrict__ w2,
    const float* __restrict__ b2, float* __restrict__ out) {
    int b = blockIdx.x;
    int tid = threadIdx.x;
    __shared__ float gvec[256];
    __shared__ float hid[256];
    gvec[tid] = g_embed[b * DD + tid];
    __syncthreads();
    float hv = b1[tid];
    for (int k = 0; k < DD; ++k) hv += gvec[k] * w1[k * DD + tid];
    hid[tid] = fmaxf(hv, 0.f);
    __syncthreads();
    float o = b2[tid];
    for (int t = 0; t < DD; ++t) o += hid[t] * w2[t * DD + tid];
    out[b * DD + tid] = o;
}

// ---------------------------------------------------------------------------
extern "C" void kernel_launch(void* const* d_in, const int* in_sizes, int n_in,
                              void* d_out, int out_size, void* d_ws, size_t ws_size,
                              hipStream_t stream) {
    const float* x        = (const float*)d_in[0];
    const float* edge_attr= (const float*)d_in[1];
    const int*   edge_idx = (const int*)d_in[2];
    const int*   batch    = (const int*)d_in[3];
    const float* enc_w    = (const float*)d_in[4];
    const float* enc_b    = (const float*)d_in[5];
    const float* eenc_w   = (const float*)d_in[6];
    const float* eenc_b   = (const float*)d_in[7];
    const float* gat_w    = (const float*)d_in[8];
    const float* att_src  = (const float*)d_in[9];
    const float* att_dst  = (const float*)d_in[10];
    const float* att_edge = (const float*)d_in[11];
    const float* gat_ew   = (const float*)d_in[12];
    const float* gat_b    = (const float*)d_in[13];
    const float* ln_g     = (const float*)d_in[14];
    const float* ln_b     = (const float*)d_in[15];
    const float* gate_w1  = (const float*)d_in[16];
    const float* gate_b1  = (const float*)d_in[17];
    const float* gate_w2  = (const float*)d_in[18];
    const float* gate_b2  = (const float*)d_in[19];
    const float* ro_w1    = (const float*)d_in[20];
    const float* ro_b1    = (const float*)d_in[21];
    const float* ro_w2    = (const float*)d_in[22];
    const float* ro_b2    = (const float*)d_in[23];
    float* out = (float*)d_out;

    const int N = in_sizes[0] / 42;       // 10000
    const int E = in_sizes[1] / 12;       // 160000
    const int Etot = E + N;               // 170000
    const int B = out_size / DD;          // 16

    // workspace carve-up (fp32 unless noted)
    char* p = (char*)d_ws;
    auto alloc = [&](size_t bytes) {
        char* r = p;
        p += (bytes + 255) & ~(size_t)255;
        return (void*)r;
    };
    float* h        = (float*)alloc((size_t)N * DD * 4);
    float* xh       = (float*)alloc((size_t)N * DD * 4);
    float* a_s      = (float*)alloc((size_t)N * HH * 4);
    float* a_d      = (float*)alloc((size_t)N * HH * 4);
    float* a_e_all  = (float*)alloc((size_t)LL * Etot * HH * 4);
    float* ae_self  = (float*)alloc((size_t)LL * N * HH * 4);
    float* wproj    = (float*)alloc((size_t)LL * DD * HH * 4);
    float* gate     = (float*)alloc((size_t)N * 4);
    float* g_embed  = (float*)alloc((size_t)B * DD * 4);
    int* deg        = (int*)alloc((size_t)N * 4);
    int* row_ptr    = (int*)alloc((size_t)(N + 1) * 4);
    int* cursor     = (int*)alloc((size_t)N * 4);
    int* csr_src    = (int*)alloc((size_t)E * 4);
    int* csr_eid    = (int*)alloc((size_t)E * 4);
    int* bstart     = (int*)alloc((size_t)(B + 1) * 4);

    const int* src_arr = edge_idx;
    const int* dst_arr = edge_idx + E;

    // zero the accumulated buffers (ws is re-poisoned 0xAA before every call)
    hipMemsetAsync(deg, 0, (size_t)N * 4, stream);
    hipMemsetAsync(ae_self, 0, (size_t)LL * N * HH * 4, stream);

    wproj_kernel<<<LL, 256, 0, stream>>>(gat_ew, att_edge, wproj);
    encoder_kernel<<<N, 256, 0, stream>>>(x, enc_w, enc_b, h, N);
    edge_pre_kernel<<<(E + 3) / 4, 256, 0, stream>>>(
        edge_attr, dst_arr, eenc_w, eenc_b, wproj, a_e_all, ae_self, deg, E, Etot, N);
    self_ae_kernel<<<(N * LL * HH + 255) / 256, 256, 0, stream>>>(
        ae_self, deg, a_e_all, N, E, Etot);
    scan_kernel<<<1, 1024, 0, stream>>>(deg, row_ptr, N);
    copy_int_kernel<<<(N + 255) / 256, 256, 0, stream>>>(row_ptr, cursor, N);
    scatter_kernel<<<(E + 255) / 256, 256, 0, stream>>>(
        src_arr, dst_arr, cursor, csr_src, csr_eid, E);

    dim3 ggrid((N + 63) / 64, 4);
    for (int l = 0; l < LL; ++l) {
        gemm256_kernel<<<ggrid, 256, 0, stream>>>(
            h, gat_w + (size_t)l * DD * DD, nullptr, xh, N, 0);
        asd_kernel<<<N, 256, 0, stream>>>(
            xh, att_src + l * DD, att_dst + l * DD, a_s, a_d);
        gat_message_kernel<<<N, 256, 0, stream>>>(
            xh, a_s, a_d, a_e_all + (size_t)l * Etot * HH, row_ptr, csr_src, csr_eid,
            gat_b + l * DD, ln_g + l * DD, ln_b + l * DD, h, N, E);
    }

    // pooling gate MLP: hidden = relu(h @ gate_w1 + gate_b1) into xh (reuse)
    gemm256_kernel<<<ggrid, 256, 0, stream>>>(h, gate_w1, gate_b1, xh, N, 1);
    gate_kernel<<<N, 256, 0, stream>>>(xh, gate_w2, gate_b2, gate, N);
    bstart_kernel<<<1, 32, 0, stream>>>(batch, bstart, N, B);
    pool_kernel<<<B, 256, 0, stream>>>(gate, h, bstart, g_embed);
    readout_kernel<<<B, 256, 0, stream>>>(g_embed, ro_w1, ro_b1, ro_w2, ro_b2, out);
}

// Round 2
// 965.175 us; speedup vs baseline: 1.2477x; 1.2477x over previous
//
#include <hip/hip_runtime.h>
#include <math.h>

// Problem constants (fixed-shape problem)
#define DD 256
#define HH 4
#define CC 64
#define LL 5
#define NEG_SLOPE 0.2f
#define LH 20  // L*H

static __device__ __forceinline__ float lrelu(float x) {
    return x > 0.0f ? x : NEG_SLOPE * x;
}

// ---------------------------------------------------------------------------
// K0: wproj[k][l*4+h] = sum_c gat_ew[l][k][h*64+c] * att_edge[l][h][c]
__global__ __launch_bounds__(256) void wproj_kernel(
    const float* __restrict__ gat_ew, const float* __restrict__ att_edge,
    float* __restrict__ wproj) {
    int k = threadIdx.x;
    for (int l = 0; l < LL; ++l) {
        const float* W = gat_ew + (size_t)l * DD * DD;
        const float* att = att_edge + l * DD;  // [H][C] flat = 256
        for (int hh = 0; hh < HH; ++hh) {
            float s = 0.f;
            #pragma unroll
            for (int c = 0; c < CC; ++c)
                s += W[k * DD + hh * CC + c] * att[hh * CC + c];
            wproj[k * LH + l * HH + hh] = s;
        }
    }
}

// ---------------------------------------------------------------------------
// K1: node encoder h = relu(x @ enc_w + enc_b)
__global__ __launch_bounds__(256) void encoder_kernel(
    const float* __restrict__ x, const float* __restrict__ enc_w,
    const float* __restrict__ enc_b, float* __restrict__ h, int N) {
    int n = blockIdx.x;
    int tid = threadIdx.x;
    __shared__ float xs[42];
    if (tid < 42) xs[tid] = x[(size_t)n * 42 + tid];
    __syncthreads();
    float acc = enc_b[tid];
    #pragma unroll
    for (int f = 0; f < 42; ++f) acc += xs[f] * enc_w[f * DD + tid];
    h[(size_t)n * DD + tid] = fmaxf(acc, 0.f);
}

// ---------------------------------------------------------------------------
// K2: per-edge a_e[e][l*4+h] = relu(edge_attr[e]@eenc_w + eenc_b) . wproj[:,l*4+h]
// 2 edges per thread; all LDS reads are wave-uniform (broadcast, conflict-free).
__global__ __launch_bounds__(256) void edge_pre_kernel(
    const float* __restrict__ edge_attr,
    const float* __restrict__ eenc_w, const float* __restrict__ eenc_b,
    const float* __restrict__ wproj, float* __restrict__ a_e_all, int E) {
    __shared__ float Wt[12 * 256];   // k-major: Wt[k*12+f]  (12 KB)
    __shared__ float wpl[256 * LH];  // wpl[k*20+j]          (20 KB)
    __shared__ float bs[256];        // eenc_b               (1 KB)
    int tid = threadIdx.x;
    for (int i = tid; i < 12 * 256; i += 256) {
        int k = i / 12, f = i % 12;
        Wt[i] = eenc_w[f * 256 + k];
    }
    for (int i = tid; i < 256 * LH; i += 256) wpl[i] = wproj[i];
    bs[tid] = eenc_b[tid];
    __syncthreads();

    int base = blockIdx.x * 512;
    int e0 = base + tid;
    int e1 = base + 256 + tid;
    bool v0 = e0 < E, v1 = e1 < E;
    float ea0[12], ea1[12];
    #pragma unroll
    for (int f = 0; f < 12; ++f) {
        ea0[f] = v0 ? edge_attr[(size_t)e0 * 12 + f] : 0.f;
        ea1[f] = v1 ? edge_attr[(size_t)e1 * 12 + f] : 0.f;
    }
    float acc0[LH] = {}, acc1[LH] = {};
    for (int k = 0; k < 256; ++k) {
        const float* wr = &Wt[k * 12];
        float m0 = bs[k], m1 = m0;
        #pragma unroll
        for (int f = 0; f < 12; ++f) {
            float w = wr[f];
            m0 += ea0[f] * w;
            m1 += ea1[f] * w;
        }
        m0 = fmaxf(m0, 0.f);
        m1 = fmaxf(m1, 0.f);
        const float* pr = &wpl[k * LH];
        #pragma unroll
        for (int j = 0; j < LH; ++j) {
            float w = pr[j];
            acc0[j] += m0 * w;
            acc1[j] += m1 * w;
        }
    }
    if (v0) {
        #pragma unroll
        for (int j = 0; j < LH; ++j) a_e_all[(size_t)e0 * LH + j] = acc0[j];
    }
    if (v1) {
        #pragma unroll
        for (int j = 0; j < LH; ++j) a_e_all[(size_t)e1 * LH + j] = acc1[j];
    }
}

// ---------------------------------------------------------------------------
// deg histogram
__global__ void deg_kernel(const int* __restrict__ dst, int* __restrict__ deg, int E) {
    int e = blockIdx.x * 256 + threadIdx.x;
    if (e < E) atomicAdd(&deg[dst[e]], 1);
}

// K3: self-loop a_e = mean of incoming real-edge a_e (via CSR, no atomics)
__global__ void self_ae_kernel(const int* __restrict__ row_ptr,
                               const int* __restrict__ csr_eid,
                               float* __restrict__ a_e_all, int N, int E) {
    int i = blockIdx.x * 256 + threadIdx.x;
    if (i >= N * LH) return;
    int n = i / LH;
    int j = i % LH;
    int rs = row_ptr[n], re = row_ptr[n + 1];
    float s = 0.f;
    for (int k = rs; k < re; ++k)
        s += a_e_all[(size_t)csr_eid[k] * LH + j];
    a_e_all[(size_t)(E + n) * LH + j] = s / (float)max(re - rs, 1);
}

// ---------------------------------------------------------------------------
// K4: exclusive prefix scan of deg -> row_ptr  (single block)
__global__ __launch_bounds__(1024) void scan_kernel(const int* __restrict__ deg,
                                                    int* __restrict__ row_ptr, int n) {
    __shared__ int buf[1024];
    __shared__ int carry_s;
    int tid = threadIdx.x;
    if (tid == 0) carry_s = 0;
    __syncthreads();
    for (int base = 0; base < n; base += 1024) {
        int i = base + tid;
        int v = (i < n) ? deg[i] : 0;
        buf[tid] = v;
        __syncthreads();
        for (int off = 1; off < 1024; off <<= 1) {
            int t = (tid >= off) ? buf[tid - off] : 0;
            __syncthreads();
            buf[tid] += t;
            __syncthreads();
        }
        int carry = carry_s;
        if (i < n) row_ptr[i] = carry + buf[tid] - v;
        __syncthreads();
        if (tid == 1023) carry_s = carry + buf[1023];
        __syncthreads();
    }
    if (tid == 0) row_ptr[n] = carry_s;
}

__global__ void copy_int_kernel(const int* __restrict__ a, int* __restrict__ b, int n) {
    int i = blockIdx.x * 256 + threadIdx.x;
    if (i < n) b[i] = a[i];
}

// K4c: scatter edges into CSR order by dst
__global__ void scatter_kernel(const int* __restrict__ src, const int* __restrict__ dst,
                               int* __restrict__ cursor, int* __restrict__ csr_src,
                               int* __restrict__ csr_eid, int E) {
    int e = blockIdx.x * 256 + threadIdx.x;
    if (e >= E) return;
    int d = dst[e];
    int pos = atomicAdd(&cursor[d], 1);
    csr_src[pos] = src[e];
    csr_eid[pos] = e;
}

// ---------------------------------------------------------------------------
// GEMM: C[M,256] = A[M,256] @ W[256,256] (+bias, optional relu). fp32, 64x64 tile.
__global__ __launch_bounds__(256) void gemm256_kernel(
    const float* __restrict__ A, const float* __restrict__ W,
    const float* __restrict__ bias, float* __restrict__ C, int M, int do_relu) {
    __shared__ float As[16][68];
    __shared__ float Bs[16][68];
    int tid = threadIdx.x;
    int tx = tid & 15, ty = tid >> 4;
    int m0 = blockIdx.x * 64;
    int n0 = blockIdx.y * 64;
    float acc[4][4] = {};
    int arow = tid >> 2, aseg = tid & 3;
    int brow = tid >> 4, bseg = tid & 15;
    for (int k0 = 0; k0 < 256; k0 += 16) {
        float4 av = make_float4(0.f, 0.f, 0.f, 0.f);
        int grow = m0 + arow;
        if (grow < M) av = *(const float4*)(A + (size_t)grow * DD + k0 + aseg * 4);
        As[aseg * 4 + 0][arow] = av.x;
        As[aseg * 4 + 1][arow] = av.y;
        As[aseg * 4 + 2][arow] = av.z;
        As[aseg * 4 + 3][arow] = av.w;
        float4 bv = *(const float4*)(W + (size_t)(k0 + brow) * DD + n0 + bseg * 4);
        *(float4*)&Bs[brow][bseg * 4] = bv;
        __syncthreads();
        #pragma unroll
        for (int kk = 0; kk < 16; ++kk) {
            float a0 = As[kk][ty * 4 + 0], a1 = As[kk][ty * 4 + 1];
            float a2 = As[kk][ty * 4 + 2], a3 = As[kk][ty * 4 + 3];
            float b0 = Bs[kk][tx * 4 + 0], b1 = Bs[kk][tx * 4 + 1];
            float b2 = Bs[kk][tx * 4 + 2], b3 = Bs[kk][tx * 4 + 3];
            acc[0][0] += a0 * b0; acc[0][1] += a0 * b1; acc[0][2] += a0 * b2; acc[0][3] += a0 * b3;
            acc[1][0] += a1 * b0; acc[1][1] += a1 * b1; acc[1][2] += a1 * b2; acc[1][3] += a1 * b3;
            acc[2][0] += a2 * b0; acc[2][1] += a2 * b1; acc[2][2] += a2 * b2; acc[2][3] += a2 * b3;
            acc[3][0] += a3 * b0; acc[3][1] += a3 * b1; acc[3][2] += a3 * b2; acc[3][3] += a3 * b3;
        }
        __syncthreads();
    }
    #pragma unroll
    for (int i = 0; i < 4; ++i) {
        int r = m0 + ty * 4 + i;
        if (r >= M) continue;
        #pragma unroll
        for (int j = 0; j < 4; ++j) {
            int col = n0 + tx * 4 + j;
            float v = acc[i][j];
            if (bias) v += bias[col];
            if (do_relu) v = fmaxf(v, 0.f);
            C[(size_t)r * DD + col] = v;
        }
    }
}

// ---------------------------------------------------------------------------
// K5b: a_s[n,h], a_d[n,h] from xh
__global__ __launch_bounds__(256) void asd_kernel(
    const float* __restrict__ xh, const float* __restrict__ att_src,
    const float* __restrict__ att_dst, float* __restrict__ a_s, float* __restrict__ a_d) {
    int n = blockIdx.x;
    int tid = threadIdx.x;
    int hh = tid >> 6;
    float v = xh[(size_t)n * DD + tid];
    float ps = v * att_src[tid];  // att_src[l] is [H][C] flat == tid
    float pd = v * att_dst[tid];
    #pragma unroll
    for (int off = 32; off; off >>= 1) {
        ps += __shfl_xor(ps, off, 64);
        pd += __shfl_xor(pd, off, 64);
    }
    if ((tid & 63) == 0) {
        a_s[n * HH + hh] = ps;
        a_d[n * HH + hh] = pd;
    }
}

// ---------------------------------------------------------------------------
// K6: per-node softmax attention + aggregation + bias + LN + relu + residual
// a_e points at a_e_all + l*HH; per-edge value at a_e[e*LH + hh]
__global__ __launch_bounds__(256) void gat_message_kernel(
    const float* __restrict__ xh, const float* __restrict__ a_s,
    const float* __restrict__ a_d, const float* __restrict__ a_e,
    const int* __restrict__ row_ptr, const int* __restrict__ csr_src,
    const int* __restrict__ csr_eid, const float* __restrict__ gat_b,
    const float* __restrict__ ln_g, const float* __restrict__ ln_b,
    float* __restrict__ h, int N, int E) {
    int n = blockIdx.x;
    int tid = threadIdx.x;
    int hh = tid >> 6, c = tid & 63;
    int rs = row_ptr[n], re = row_ptr[n + 1];
    float adn = a_d[n * HH + hh];
    float al_self = lrelu(a_s[n * HH + hh] + adn + a_e[(size_t)(E + n) * LH + hh]);
    // pass 1: max
    float m = al_self;
    for (int k = rs + c; k < re; k += 64) {
        int s = csr_src[k], eid = csr_eid[k];
        m = fmaxf(m, lrelu(a_s[s * HH + hh] + adn + a_e[(size_t)eid * LH + hh]));
    }
    #pragma unroll
    for (int off = 32; off; off >>= 1) m = fmaxf(m, __shfl_xor(m, off, 64));
    // pass 2: denom
    float sden = 0.f;
    for (int k = rs + c; k < re; k += 64) {
        int s = csr_src[k], eid = csr_eid[k];
        sden += __expf(lrelu(a_s[s * HH + hh] + adn + a_e[(size_t)eid * LH + hh]) - m);
    }
    #pragma unroll
    for (int off = 32; off; off >>= 1) sden += __shfl_xor(sden, off, 64);
    sden += __expf(al_self - m);
    float inv_den = 1.0f / sden;
    // pass 3: weighted aggregation (all lanes walk all edges; xh row reads coalesced)
    float acc = __expf(al_self - m) * inv_den * xh[(size_t)n * DD + hh * CC + c];
    for (int k = rs; k < re; ++k) {
        int s = csr_src[k], eid = csr_eid[k];
        float w = __expf(lrelu(a_s[s * HH + hh] + adn + a_e[(size_t)eid * LH + hh]) - m) * inv_den;
        acc += w * xh[(size_t)s * DD + hh * CC + c];
    }
    float val = acc + gat_b[tid];
    // layernorm over 256
    __shared__ float s1[256], s2[256];
    s1[tid] = val;
    s2[tid] = val * val;
    __syncthreads();
    for (int off = 128; off; off >>= 1) {
        if (tid < off) { s1[tid] += s1[tid + off]; s2[tid] += s2[tid + off]; }
        __syncthreads();
    }
    float mu = s1[0] * (1.0f / DD);
    float var = s2[0] * (1.0f / DD) - mu * mu;
    float normed = (val - mu) * rsqrtf(var + 1e-5f) * ln_g[tid] + ln_b[tid];
    h[(size_t)n * DD + tid] += fmaxf(normed, 0.f);
}

// ---------------------------------------------------------------------------
// K7b: gate scalar per node
__global__ __launch_bounds__(256) void gate_kernel(
    const float* __restrict__ hid, const float* __restrict__ w2,
    const float* __restrict__ b2, float* __restrict__ gate, int N) {
    int n = blockIdx.x;
    int tid = threadIdx.x;
    __shared__ float red[256];
    red[tid] = hid[(size_t)n * DD + tid] * w2[tid];
    __syncthreads();
    for (int off = 128; off; off >>= 1) {
        if (tid < off) red[tid] += red[tid + off];
        __syncthreads();
    }
    if (tid == 0) gate[n] = red[0] + b2[0];
}

// K7pre: batch segment boundaries (batch is sorted)
__global__ void bstart_kernel(const int* __restrict__ batch, int* __restrict__ bstart,
                              int N, int B) {
    int b = threadIdx.x;
    if (b > B) return;
    int lo = 0, hi = N;
    while (lo < hi) {
        int mid = (lo + hi) >> 1;
        if (batch[mid] < b) lo = mid + 1; else hi = mid;
    }
    bstart[b] = lo;
}

// K7pool: per-graph softmax pooling
__global__ __launch_bounds__(256) void pool_kernel(
    const float* __restrict__ gate, const float* __restrict__ h,
    const int* __restrict__ bstart, float* __restrict__ g_embed) {
    int b = blockIdx.x;
    int tid = threadIdx.x;
    int s0 = bstart[b], s1 = bstart[b + 1];
    __shared__ float red[256];
    if (s1 == s0) { g_embed[b * DD + tid] = 0.f; return; }
    float m = -1e30f;
    for (int i = s0 + tid; i < s1; i += 256) m = fmaxf(m, gate[i]);
    red[tid] = m;
    __syncthreads();
    for (int off = 128; off; off >>= 1) {
        if (tid < off) red[tid] = fmaxf(red[tid], red[tid + off]);
        __syncthreads();
    }
    float gm = red[0];
    __syncthreads();
    float s = 0.f;
    for (int i = s0 + tid; i < s1; i += 256) s += __expf(gate[i] - gm);
    red[tid] = s;
    __syncthreads();
    for (int off = 128; off; off >>= 1) {
        if (tid < off) red[tid] += red[tid + off];
        __syncthreads();
    }
    float inv = 1.0f / red[0];
    float acc = 0.f;
    for (int i = s0; i < s1; ++i)
        acc += __expf(gate[i] - gm) * h[(size_t)i * DD + tid];
    g_embed[b * DD + tid] = acc * inv;
}

// K8: readout MLP [B,256] -> [B,256]
__global__ __launch_bounds__(256) void readout_kernel(
    const float* __restrict__ g_embed, const float* __restrict__ w1,
    const float* __restrict__ b1, const float* __restrict__ w2,
    const float* __restrict__ b2, float* __restrict__ out) {
    int b = blockIdx.x;
    int tid = threadIdx.x;
    __shared__ float gvec[256];
    __shared__ float hid[256];
    gvec[tid] = g_embed[b * DD + tid];
    __syncthreads();
    float hv = b1[tid];
    for (int k = 0; k < DD; ++k) hv += gvec[k] * w1[k * DD + tid];
    hid[tid] = fmaxf(hv, 0.f);
    __syncthreads();
    float o = b2[tid];
    for (int t = 0; t < DD; ++t) o += hid[t] * w2[t * DD + tid];
    out[b * DD + tid] = o;
}

// ---------------------------------------------------------------------------
extern "C" void kernel_launch(void* const* d_in, const int* in_sizes, int n_in,
                              void* d_out, int out_size, void* d_ws, size_t ws_size,
                              hipStream_t stream) {
    const float* x        = (const float*)d_in[0];
    const float* edge_attr= (const float*)d_in[1];
    const int*   edge_idx = (const int*)d_in[2];
    const int*   batch    = (const int*)d_in[3];
    const float* enc_w    = (const float*)d_in[4];
    const float* enc_b    = (const float*)d_in[5];
    const float* eenc_w   = (const float*)d_in[6];
    const float* eenc_b   = (const float*)d_in[7];
    const float* gat_w    = (const float*)d_in[8];
    const float* att_src  = (const float*)d_in[9];
    const float* att_dst  = (const float*)d_in[10];
    const float* att_edge = (const float*)d_in[11];
    const float* gat_ew   = (const float*)d_in[12];
    const float* gat_b    = (const float*)d_in[13];
    const float* ln_g     = (const float*)d_in[14];
    const float* ln_b     = (const float*)d_in[15];
    const float* gate_w1  = (const float*)d_in[16];
    const float* gate_b1  = (const float*)d_in[17];
    const float* gate_w2  = (const float*)d_in[18];
    const float* gate_b2  = (const float*)d_in[19];
    const float* ro_w1    = (const float*)d_in[20];
    const float* ro_b1    = (const float*)d_in[21];
    const float* ro_w2    = (const float*)d_in[22];
    const float* ro_b2    = (const float*)d_in[23];
    float* out = (float*)d_out;

    const int N = in_sizes[0] / 42;       // 10000
    const int E = in_sizes[1] / 12;       // 160000
    const int B = out_size / DD;          // 16

    // workspace carve-up
    char* p = (char*)d_ws;
    auto alloc = [&](size_t bytes) {
        char* r = p;
        p += (bytes + 255) & ~(size_t)255;
        return (void*)r;
    };
    float* h        = (float*)alloc((size_t)N * DD * 4);
    float* xh       = (float*)alloc((size_t)N * DD * 4);
    float* a_s      = (float*)alloc((size_t)N * HH * 4);
    float* a_d      = (float*)alloc((size_t)N * HH * 4);
    float* a_e_all  = (float*)alloc((size_t)(E + N) * LH * 4);  // [e][l*4+h]
    float* wproj    = (float*)alloc((size_t)DD * LH * 4);
    float* gate     = (float*)alloc((size_t)N * 4);
    float* g_embed  = (float*)alloc((size_t)B * DD * 4);
    int* deg        = (int*)alloc((size_t)N * 4);
    int* row_ptr    = (int*)alloc((size_t)(N + 1) * 4);
    int* cursor     = (int*)alloc((size_t)N * 4);
    int* csr_src    = (int*)alloc((size_t)E * 4);
    int* csr_eid    = (int*)alloc((size_t)E * 4);
    int* bstart     = (int*)alloc((size_t)(B + 1) * 4);

    const int* src_arr = edge_idx;
    const int* dst_arr = edge_idx + E;

    hipMemsetAsync(deg, 0, (size_t)N * 4, stream);

    wproj_kernel<<<1, 256, 0, stream>>>(gat_ew, att_edge, wproj);
    encoder_kernel<<<N, 256, 0, stream>>>(x, enc_w, enc_b, h, N);
    deg_kernel<<<(E + 255) / 256, 256, 0, stream>>>(dst_arr, deg, E);
    scan_kernel<<<1, 1024, 0, stream>>>(deg, row_ptr, N);
    copy_int_kernel<<<(N + 255) / 256, 256, 0, stream>>>(row_ptr, cursor, N);
    scatter_kernel<<<(E + 255) / 256, 256, 0, stream>>>(
        src_arr, dst_arr, cursor, csr_src, csr_eid, E);
    edge_pre_kernel<<<(E + 511) / 512, 256, 0, stream>>>(
        edge_attr, eenc_w, eenc_b, wproj, a_e_all, E);
    self_ae_kernel<<<(N * LH + 255) / 256, 256, 0, stream>>>(
        row_ptr, csr_eid, a_e_all, N, E);

    dim3 ggrid((N + 63) / 64, 4);
    for (int l = 0; l < LL; ++l) {
        gemm256_kernel<<<ggrid, 256, 0, stream>>>(
            h, gat_w + (size_t)l * DD * DD, nullptr, xh, N, 0);
        asd_kernel<<<N, 256, 0, stream>>>(
            xh, att_src + l * DD, att_dst + l * DD, a_s, a_d);
        gat_message_kernel<<<N, 256, 0, stream>>>(
            xh, a_s, a_d, a_e_all + l * HH, row_ptr, csr_src, csr_eid,
            gat_b + l * DD, ln_g + l * DD, ln_b + l * DD, h, N, E);
    }

    // pooling gate MLP: hidden = relu(h @ gate_w1 + gate_b1) into xh (reuse)
    gemm256_kernel<<<ggrid, 256, 0, stream>>>(h, gate_w1, gate_b1, xh, N, 1);
    gate_kernel<<<N, 256, 0, stream>>>(xh, gate_w2, gate_b2, gate, N);
    bstart_kernel<<<1, 32, 0, stream>>>(batch, bstart, N, B);
    pool_kernel<<<B, 256, 0, stream>>>(gate, h, bstart, g_embed);
    readout_kernel<<<B, 256, 0, stream>>>(g_embed, ro_w1, ro_b1, ro_w2, ro_b2, out);
}

// Round 3
// 828.282 us; speedup vs baseline: 1.4539x; 1.1653x over previous
//
#include <hip/hip_runtime.h>
#include <math.h>

// Problem constants (fixed-shape problem)
#define DD 256
#define HH 4
#define CC 64
#define LL 5
#define NEG_SLOPE 0.2f
#define LH 20  // L*H

static __device__ __forceinline__ float lrelu(float x) {
    return x > 0.0f ? x : NEG_SLOPE * x;
}

// ---------------------------------------------------------------------------
// K0: wproj[k][l*4+h] = sum_c gat_ew[l][k][h*64+c] * att_edge[l][h][c]
__global__ __launch_bounds__(256) void wproj_kernel(
    const float* __restrict__ gat_ew, const float* __restrict__ att_edge,
    float* __restrict__ wproj) {
    int k = threadIdx.x;
    for (int l = 0; l < LL; ++l) {
        const float* W = gat_ew + (size_t)l * DD * DD;
        const float* att = att_edge + l * DD;  // [H][C] flat = 256
        for (int hh = 0; hh < HH; ++hh) {
            float s = 0.f;
            #pragma unroll
            for (int c = 0; c < CC; ++c)
                s += W[k * DD + hh * CC + c] * att[hh * CC + c];
            wproj[k * LH + l * HH + hh] = s;
        }
    }
}

// ---------------------------------------------------------------------------
// K1: node encoder h = relu(x @ enc_w + enc_b)
__global__ __launch_bounds__(256) void encoder_kernel(
    const float* __restrict__ x, const float* __restrict__ enc_w,
    const float* __restrict__ enc_b, float* __restrict__ h, int N) {
    int n = blockIdx.x;
    int tid = threadIdx.x;
    __shared__ float xs[42];
    if (tid < 42) xs[tid] = x[(size_t)n * 42 + tid];
    __syncthreads();
    float acc = enc_b[tid];
    #pragma unroll
    for (int f = 0; f < 42; ++f) acc += xs[f] * enc_w[f * DD + tid];
    h[(size_t)n * DD + tid] = fmaxf(acc, 0.f);
}

// ---------------------------------------------------------------------------
// K2: per-edge a_e[e][l*4+h] = relu(edge_attr[e]@eenc_w + eenc_b) . wproj[:,l*4+h]
// 2 edges per thread; all LDS reads are wave-uniform (broadcast, conflict-free).
__global__ __launch_bounds__(256) void edge_pre_kernel(
    const float* __restrict__ edge_attr,
    const float* __restrict__ eenc_w, const float* __restrict__ eenc_b,
    const float* __restrict__ wproj, float* __restrict__ a_e_all, int E) {
    __shared__ float Wt[12 * 256];   // k-major: Wt[k*12+f]  (12 KB)
    __shared__ float wpl[256 * LH];  // wpl[k*20+j]          (20 KB)
    __shared__ float bs[256];        // eenc_b               (1 KB)
    int tid = threadIdx.x;
    for (int i = tid; i < 12 * 256; i += 256) {
        int k = i / 12, f = i % 12;
        Wt[i] = eenc_w[f * 256 + k];
    }
    for (int i = tid; i < 256 * LH; i += 256) wpl[i] = wproj[i];
    bs[tid] = eenc_b[tid];
    __syncthreads();

    int base = blockIdx.x * 512;
    int e0 = base + tid;
    int e1 = base + 256 + tid;
    bool v0 = e0 < E, v1 = e1 < E;
    float ea0[12], ea1[12];
    #pragma unroll
    for (int f = 0; f < 12; ++f) {
        ea0[f] = v0 ? edge_attr[(size_t)e0 * 12 + f] : 0.f;
        ea1[f] = v1 ? edge_attr[(size_t)e1 * 12 + f] : 0.f;
    }
    float acc0[LH] = {}, acc1[LH] = {};
    for (int k = 0; k < 256; ++k) {
        const float* wr = &Wt[k * 12];
        float m0 = bs[k], m1 = m0;
        #pragma unroll
        for (int f = 0; f < 12; ++f) {
            float w = wr[f];
            m0 += ea0[f] * w;
            m1 += ea1[f] * w;
        }
        m0 = fmaxf(m0, 0.f);
        m1 = fmaxf(m1, 0.f);
        const float* pr = &wpl[k * LH];
        #pragma unroll
        for (int j = 0; j < LH; ++j) {
            float w = pr[j];
            acc0[j] += m0 * w;
            acc1[j] += m1 * w;
        }
    }
    if (v0) {
        #pragma unroll
        for (int j = 0; j < LH; ++j) a_e_all[(size_t)e0 * LH + j] = acc0[j];
    }
    if (v1) {
        #pragma unroll
        for (int j = 0; j < LH; ++j) a_e_all[(size_t)e1 * LH + j] = acc1[j];
    }
}

// ---------------------------------------------------------------------------
// deg histogram
__global__ void deg_kernel(const int* __restrict__ dst, int* __restrict__ deg, int E) {
    int e = blockIdx.x * 256 + threadIdx.x;
    if (e < E) atomicAdd(&deg[dst[e]], 1);
}

// K3: self-loop a_e = mean of incoming real-edge a_e (via CSR, no atomics)
__global__ void self_ae_kernel(const int* __restrict__ row_ptr,
                               const int* __restrict__ csr_eid,
                               float* __restrict__ a_e_all, int N, int E) {
    int i = blockIdx.x * 256 + threadIdx.x;
    if (i >= N * LH) return;
    int n = i / LH;
    int j = i % LH;
    int rs = row_ptr[n], re = row_ptr[n + 1];
    float s = 0.f;
    for (int k = rs; k < re; ++k)
        s += a_e_all[(size_t)csr_eid[k] * LH + j];
    a_e_all[(size_t)(E + n) * LH + j] = s / (float)max(re - rs, 1);
}

// ---------------------------------------------------------------------------
// K4: exclusive prefix scan of deg -> row_ptr  (single block)
__global__ __launch_bounds__(1024) void scan_kernel(const int* __restrict__ deg,
                                                    int* __restrict__ row_ptr, int n) {
    __shared__ int buf[1024];
    __shared__ int carry_s;
    int tid = threadIdx.x;
    if (tid == 0) carry_s = 0;
    __syncthreads();
    for (int base = 0; base < n; base += 1024) {
        int i = base + tid;
        int v = (i < n) ? deg[i] : 0;
        buf[tid] = v;
        __syncthreads();
        for (int off = 1; off < 1024; off <<= 1) {
            int t = (tid >= off) ? buf[tid - off] : 0;
            __syncthreads();
            buf[tid] += t;
            __syncthreads();
        }
        int carry = carry_s;
        if (i < n) row_ptr[i] = carry + buf[tid] - v;
        __syncthreads();
        if (tid == 1023) carry_s = carry + buf[1023];
        __syncthreads();
    }
    if (tid == 0) row_ptr[n] = carry_s;
}

__global__ void copy_int_kernel(const int* __restrict__ a, int* __restrict__ b, int n) {
    int i = blockIdx.x * 256 + threadIdx.x;
    if (i < n) b[i] = a[i];
}

// K4c: scatter edges into CSR order by dst
__global__ void scatter_kernel(const int* __restrict__ src, const int* __restrict__ dst,
                               int* __restrict__ cursor, int* __restrict__ csr_src,
                               int* __restrict__ csr_eid, int E) {
    int e = blockIdx.x * 256 + threadIdx.x;
    if (e >= E) return;
    int d = dst[e];
    int pos = atomicAdd(&cursor[d], 1);
    csr_src[pos] = src[e];
    csr_eid[pos] = e;
}

// ---------------------------------------------------------------------------
// GEMM: C[M,256] = A[M,256] @ W[256,256] (+bias, optional relu). fp32, 64x64 tile.
__global__ __launch_bounds__(256) void gemm256_kernel(
    const float* __restrict__ A, const float* __restrict__ W,
    const float* __restrict__ bias, float* __restrict__ C, int M, int do_relu) {
    __shared__ float As[16][68];
    __shared__ float Bs[16][68];
    int tid = threadIdx.x;
    int tx = tid & 15, ty = tid >> 4;
    int m0 = blockIdx.x * 64;
    int n0 = blockIdx.y * 64;
    float acc[4][4] = {};
    int arow = tid >> 2, aseg = tid & 3;
    int brow = tid >> 4, bseg = tid & 15;
    for (int k0 = 0; k0 < 256; k0 += 16) {
        float4 av = make_float4(0.f, 0.f, 0.f, 0.f);
        int grow = m0 + arow;
        if (grow < M) av = *(const float4*)(A + (size_t)grow * DD + k0 + aseg * 4);
        As[aseg * 4 + 0][arow] = av.x;
        As[aseg * 4 + 1][arow] = av.y;
        As[aseg * 4 + 2][arow] = av.z;
        As[aseg * 4 + 3][arow] = av.w;
        float4 bv = *(const float4*)(W + (size_t)(k0 + brow) * DD + n0 + bseg * 4);
        *(float4*)&Bs[brow][bseg * 4] = bv;
        __syncthreads();
        #pragma unroll
        for (int kk = 0; kk < 16; ++kk) {
            float a0 = As[kk][ty * 4 + 0], a1 = As[kk][ty * 4 + 1];
            float a2 = As[kk][ty * 4 + 2], a3 = As[kk][ty * 4 + 3];
            float b0 = Bs[kk][tx * 4 + 0], b1 = Bs[kk][tx * 4 + 1];
            float b2 = Bs[kk][tx * 4 + 2], b3 = Bs[kk][tx * 4 + 3];
            acc[0][0] += a0 * b0; acc[0][1] += a0 * b1; acc[0][2] += a0 * b2; acc[0][3] += a0 * b3;
            acc[1][0] += a1 * b0; acc[1][1] += a1 * b1; acc[1][2] += a1 * b2; acc[1][3] += a1 * b3;
            acc[2][0] += a2 * b0; acc[2][1] += a2 * b1; acc[2][2] += a2 * b2; acc[2][3] += a2 * b3;
            acc[3][0] += a3 * b0; acc[3][1] += a3 * b1; acc[3][2] += a3 * b2; acc[3][3] += a3 * b3;
        }
        __syncthreads();
    }
    #pragma unroll
    for (int i = 0; i < 4; ++i) {
        int r = m0 + ty * 4 + i;
        if (r >= M) continue;
        #pragma unroll
        for (int j = 0; j < 4; ++j) {
            int col = n0 + tx * 4 + j;
            float v = acc[i][j];
            if (bias) v += bias[col];
            if (do_relu) v = fmaxf(v, 0.f);
            C[(size_t)r * DD + col] = v;
        }
    }
}

// ---------------------------------------------------------------------------
// K5b: a_s[n,h], a_d[n,h] from xh
__global__ __launch_bounds__(256) void asd_kernel(
    const float* __restrict__ xh, const float* __restrict__ att_src,
    const float* __restrict__ att_dst, float* __restrict__ a_s, float* __restrict__ a_d) {
    int n = blockIdx.x;
    int tid = threadIdx.x;
    int hh = tid >> 6;
    float v = xh[(size_t)n * DD + tid];
    float ps = v * att_src[tid];  // att_src[l] is [H][C] flat == tid
    float pd = v * att_dst[tid];
    #pragma unroll
    for (int off = 32; off; off >>= 1) {
        ps += __shfl_xor(ps, off, 64);
        pd += __shfl_xor(pd, off, 64);
    }
    if ((tid & 63) == 0) {
        a_s[n * HH + hh] = ps;
        a_d[n * HH + hh] = pd;
    }
}

// ---------------------------------------------------------------------------
// K6: per-node softmax attention + aggregation + bias + LN + relu + residual
// a_e points at a_e_all + l*HH; per-edge value at a_e[e*LH + hh]
__global__ __launch_bounds__(256) void gat_message_kernel(
    const float* __restrict__ xh, const float* __restrict__ a_s,
    const float* __restrict__ a_d, const float* __restrict__ a_e,
    const int* __restrict__ row_ptr, const int* __restrict__ csr_src,
    const int* __restrict__ csr_eid, const float* __restrict__ gat_b,
    const float* __restrict__ ln_g, const float* __restrict__ ln_b,
    float* __restrict__ h, int N, int E) {
    int n = blockIdx.x;
    int tid = threadIdx.x;
    int hh = tid >> 6, c = tid & 63;
    int rs = row_ptr[n], re = row_ptr[n + 1];
    float adn = a_d[n * HH + hh];
    float al_self = lrelu(a_s[n * HH + hh] + adn + a_e[(size_t)(E + n) * LH + hh]);
    // pass 1: max
    float m = al_self;
    for (int k = rs + c; k < re; k += 64) {
        int s = csr_src[k], eid = csr_eid[k];
        m = fmaxf(m, lrelu(a_s[s * HH + hh] + adn + a_e[(size_t)eid * LH + hh]));
    }
    #pragma unroll
    for (int off = 32; off; off >>= 1) m = fmaxf(m, __shfl_xor(m, off, 64));
    // pass 2: denom
    float sden = 0.f;
    for (int k = rs + c; k < re; k += 64) {
        int s = csr_src[k], eid = csr_eid[k];
        sden += __expf(lrelu(a_s[s * HH + hh] + adn + a_e[(size_t)eid * LH + hh]) - m);
    }
    #pragma unroll
    for (int off = 32; off; off >>= 1) sden += __shfl_xor(sden, off, 64);
    sden += __expf(al_self - m);
    float inv_den = 1.0f / sden;
    // pass 3: weighted aggregation (all lanes walk all edges; xh row reads coalesced)
    float acc = __expf(al_self - m) * inv_den * xh[(size_t)n * DD + hh * CC + c];
    for (int k = rs; k < re; ++k) {
        int s = csr_src[k], eid = csr_eid[k];
        float w = __expf(lrelu(a_s[s * HH + hh] + adn + a_e[(size_t)eid * LH + hh]) - m) * inv_den;
        acc += w * xh[(size_t)s * DD + hh * CC + c];
    }
    float val = acc + gat_b[tid];
    // layernorm over 256
    __shared__ float s1[256], s2[256];
    s1[tid] = val;
    s2[tid] = val * val;
    __syncthreads();
    for (int off = 128; off; off >>= 1) {
        if (tid < off) { s1[tid] += s1[tid + off]; s2[tid] += s2[tid + off]; }
        __syncthreads();
    }
    float mu = s1[0] * (1.0f / DD);
    float var = s2[0] * (1.0f / DD) - mu * mu;
    float normed = (val - mu) * rsqrtf(var + 1e-5f) * ln_g[tid] + ln_b[tid];
    h[(size_t)n * DD + tid] += fmaxf(normed, 0.f);
}

// ---------------------------------------------------------------------------
// K7b: gate scalar per node
__global__ __launch_bounds__(256) void gate_kernel(
    const float* __restrict__ hid, const float* __restrict__ w2,
    const float* __restrict__ b2, float* __restrict__ gate, int N) {
    int n = blockIdx.x;
    int tid = threadIdx.x;
    __shared__ float red[256];
    red[tid] = hid[(size_t)n * DD + tid] * w2[tid];
    __syncthreads();
    for (int off = 128; off; off >>= 1) {
        if (tid < off) red[tid] += red[tid + off];
        __syncthreads();
    }
    if (tid == 0) gate[n] = red[0] + b2[0];
}

// K7pre: batch segment boundaries (batch is sorted)
__global__ void bstart_kernel(const int* __restrict__ batch, int* __restrict__ bstart,
                              int N, int B) {
    int b = threadIdx.x;
    if (b > B) return;
    int lo = 0, hi = N;
    while (lo < hi) {
        int mid = (lo + hi) >> 1;
        if (batch[mid] < b) lo = mid + 1; else hi = mid;
    }
    bstart[b] = lo;
}

// K7a: per-graph gate max + denom (B blocks)
__global__ __launch_bounds__(256) void gseg_kernel(
    const float* __restrict__ gate, const int* __restrict__ bstart,
    float* __restrict__ gmax, float* __restrict__ gden) {
    int b = blockIdx.x;
    int tid = threadIdx.x;
    int s0 = bstart[b], s1 = bstart[b + 1];
    __shared__ float red[256];
    float m = -1e30f;
    for (int i = s0 + tid; i < s1; i += 256) m = fmaxf(m, gate[i]);
    red[tid] = m;
    __syncthreads();
    for (int off = 128; off; off >>= 1) {
        if (tid < off) red[tid] = fmaxf(red[tid], red[tid + off]);
        __syncthreads();
    }
    float gm = red[0];
    __syncthreads();
    float s = 0.f;
    for (int i = s0 + tid; i < s1; i += 256) s += __expf(gate[i] - gm);
    red[tid] = s;
    __syncthreads();
    for (int off = 128; off; off >>= 1) {
        if (tid < off) red[tid] += red[tid + off];
        __syncthreads();
    }
    if (tid == 0) {
        gmax[b] = gm;
        gden[b] = red[0];
    }
}

// K7c: per-node pooling weight
__global__ void wgt_kernel(const float* __restrict__ gate, const int* __restrict__ batch,
                           const float* __restrict__ gmax, const float* __restrict__ gden,
                           float* __restrict__ wgt, int N) {
    int n = blockIdx.x * 256 + threadIdx.x;
    if (n >= N) return;
    int b = batch[n];
    wgt[n] = __expf(gate[n] - gmax[b]) / gden[b];
}

// K7d: scatter-accumulate pooled embedding. Each block: 32 consecutive nodes,
// register accumulate per dim (d = tid), flush on graph-boundary via atomicAdd.
#define POOL_CHUNK 32
__global__ __launch_bounds__(256) void pool_scatter_kernel(
    const float* __restrict__ h, const float* __restrict__ wgt,
    const int* __restrict__ batch, float* __restrict__ g_embed, int N) {
    int i0 = blockIdx.x * POOL_CHUNK;
    int d = threadIdx.x;
    int iend = min(i0 + POOL_CHUNK, N);
    float acc = 0.f;
    int cur = batch[i0];
    for (int i = i0; i < iend; ++i) {
        int b = batch[i];
        if (b != cur) {
            atomicAdd(&g_embed[cur * DD + d], acc);
            acc = 0.f;
            cur = b;
        }
        acc += wgt[i] * h[(size_t)i * DD + d];
    }
    atomicAdd(&g_embed[cur * DD + d], acc);
}

// K8: readout MLP [B,256] -> [B,256]
__global__ __launch_bounds__(256) void readout_kernel(
    const float* __restrict__ g_embed, const float* __restrict__ w1,
    const float* __restrict__ b1, const float* __restrict__ w2,
    const float* __restrict__ b2, float* __restrict__ out) {
    int b = blockIdx.x;
    int tid = threadIdx.x;
    __shared__ float gvec[256];
    __shared__ float hid[256];
    gvec[tid] = g_embed[b * DD + tid];
    __syncthreads();
    float hv = b1[tid];
    for (int k = 0; k < DD; ++k) hv += gvec[k] * w1[k * DD + tid];
    hid[tid] = fmaxf(hv, 0.f);
    __syncthreads();
    float o = b2[tid];
    for (int t = 0; t < DD; ++t) o += hid[t] * w2[t * DD + tid];
    out[b * DD + tid] = o;
}

// ---------------------------------------------------------------------------
extern "C" void kernel_launch(void* const* d_in, const int* in_sizes, int n_in,
                              void* d_out, int out_size, void* d_ws, size_t ws_size,
                              hipStream_t stream) {
    const float* x        = (const float*)d_in[0];
    const float* edge_attr= (const float*)d_in[1];
    const int*   edge_idx = (const int*)d_in[2];
    const int*   batch    = (const int*)d_in[3];
    const float* enc_w    = (const float*)d_in[4];
    const float* enc_b    = (const float*)d_in[5];
    const float* eenc_w   = (const float*)d_in[6];
    const float* eenc_b   = (const float*)d_in[7];
    const float* gat_w    = (const float*)d_in[8];
    const float* att_src  = (const float*)d_in[9];
    const float* att_dst  = (const float*)d_in[10];
    const float* att_edge = (const float*)d_in[11];
    const float* gat_ew   = (const float*)d_in[12];
    const float* gat_b    = (const float*)d_in[13];
    const float* ln_g     = (const float*)d_in[14];
    const float* ln_b     = (const float*)d_in[15];
    const float* gate_w1  = (const float*)d_in[16];
    const float* gate_b1  = (const float*)d_in[17];
    const float* gate_w2  = (const float*)d_in[18];
    const float* gate_b2  = (const float*)d_in[19];
    const float* ro_w1    = (const float*)d_in[20];
    const float* ro_b1    = (const float*)d_in[21];
    const float* ro_w2    = (const float*)d_in[22];
    const float* ro_b2    = (const float*)d_in[23];
    float* out = (float*)d_out;

    const int N = in_sizes[0] / 42;       // 10000
    const int E = in_sizes[1] / 12;       // 160000
    const int B = out_size / DD;          // 16

    // workspace carve-up
    char* p = (char*)d_ws;
    auto alloc = [&](size_t bytes) {
        char* r = p;
        p += (bytes + 255) & ~(size_t)255;
        return (void*)r;
    };
    float* h        = (float*)alloc((size_t)N * DD * 4);
    float* xh       = (float*)alloc((size_t)N * DD * 4);
    float* a_s      = (float*)alloc((size_t)N * HH * 4);
    float* a_d      = (float*)alloc((size_t)N * HH * 4);
    float* a_e_all  = (float*)alloc((size_t)(E + N) * LH * 4);  // [e][l*4+h]
    float* wproj    = (float*)alloc((size_t)DD * LH * 4);
    float* gate     = (float*)alloc((size_t)N * 4);
    float* g_embed  = (float*)alloc((size_t)B * DD * 4);
    float* gmax     = (float*)alloc((size_t)B * 4);
    float* gden     = (float*)alloc((size_t)B * 4);
    float* wgt      = (float*)alloc((size_t)N * 4);
    int* deg        = (int*)alloc((size_t)N * 4);
    int* row_ptr    = (int*)alloc((size_t)(N + 1) * 4);
    int* cursor     = (int*)alloc((size_t)N * 4);
    int* csr_src    = (int*)alloc((size_t)E * 4);
    int* csr_eid    = (int*)alloc((size_t)E * 4);
    int* bstart     = (int*)alloc((size_t)(B + 1) * 4);

    const int* src_arr = edge_idx;
    const int* dst_arr = edge_idx + E;

    hipMemsetAsync(deg, 0, (size_t)N * 4, stream);
    hipMemsetAsync(g_embed, 0, (size_t)B * DD * 4, stream);

    wproj_kernel<<<1, 256, 0, stream>>>(gat_ew, att_edge, wproj);
    encoder_kernel<<<N, 256, 0, stream>>>(x, enc_w, enc_b, h, N);
    deg_kernel<<<(E + 255) / 256, 256, 0, stream>>>(dst_arr, deg, E);
    scan_kernel<<<1, 1024, 0, stream>>>(deg, row_ptr, N);
    copy_int_kernel<<<(N + 255) / 256, 256, 0, stream>>>(row_ptr, cursor, N);
    scatter_kernel<<<(E + 255) / 256, 256, 0, stream>>>(
        src_arr, dst_arr, cursor, csr_src, csr_eid, E);
    edge_pre_kernel<<<(E + 511) / 512, 256, 0, stream>>>(
        edge_attr, eenc_w, eenc_b, wproj, a_e_all, E);
    self_ae_kernel<<<(N * LH + 255) / 256, 256, 0, stream>>>(
        row_ptr, csr_eid, a_e_all, N, E);

    dim3 ggrid((N + 63) / 64, 4);
    for (int l = 0; l < LL; ++l) {
        gemm256_kernel<<<ggrid, 256, 0, stream>>>(
            h, gat_w + (size_t)l * DD * DD, nullptr, xh, N, 0);
        asd_kernel<<<N, 256, 0, stream>>>(
            xh, att_src + l * DD, att_dst + l * DD, a_s, a_d);
        gat_message_kernel<<<N, 256, 0, stream>>>(
            xh, a_s, a_d, a_e_all + l * HH, row_ptr, csr_src, csr_eid,
            gat_b + l * DD, ln_g + l * DD, ln_b + l * DD, h, N, E);
    }

    // pooling gate MLP: hidden = relu(h @ gate_w1 + gate_b1) into xh (reuse)
    gemm256_kernel<<<ggrid, 256, 0, stream>>>(h, gate_w1, gate_b1, xh, N, 1);
    gate_kernel<<<N, 256, 0, stream>>>(xh, gate_w2, gate_b2, gate, N);
    bstart_kernel<<<1, 32, 0, stream>>>(batch, bstart, N, B);
    gseg_kernel<<<B, 256, 0, stream>>>(gate, bstart, gmax, gden);
    wgt_kernel<<<(N + 255) / 256, 256, 0, stream>>>(gate, batch, gmax, gden, wgt, N);
    pool_scatter_kernel<<<(N + POOL_CHUNK - 1) / POOL_CHUNK, 256, 0, stream>>>(
        h, wgt, batch, g_embed, N);
    readout_kernel<<<B, 256, 0, stream>>>(g_embed, ro_w1, ro_b1, ro_w2, ro_b2, out);
}